// Round 10
// baseline (55.266 us; speedup 1.0000x reference)
//
#include <hip/hip_runtime.h>

#define D     256
#define BATCH 4096
#define NMOM  31   // Taylor terms n = 0..30

typedef __attribute__((ext_vector_type(8))) short short8;
typedef __attribute__((ext_vector_type(4))) short short4e;
typedef __attribute__((ext_vector_type(4))) float f32x4;

__constant__ float INVFACT[NMOM] = {
    1.0f, 1.0f, 0.5f,
    1.6666666666666666e-01f, 4.1666666666666664e-02f, 8.3333333333333332e-03f,
    1.3888888888888889e-03f, 1.9841269841269841e-04f, 2.4801587301587302e-05f,
    2.7557319223985893e-06f, 2.7557319223985888e-07f, 2.5052108385441720e-08f,
    2.0876756987868100e-09f, 1.6059043836821613e-10f, 1.1470745597729725e-11f,
    7.6471637318198164e-13f, 4.7794773323873853e-14f, 2.8114572543455206e-15f,
    1.5619206968586225e-16f, 8.2206352466243295e-18f, 4.1103176233121648e-19f,
    1.9572941063391263e-20f, 8.8967913924505741e-22f, 3.8681701706306843e-23f,
    1.6117375710961184e-24f, 6.4469502843844735e-26f, 2.4795962632247972e-27f,
    9.1836898637955460e-29f, 3.2798892370698379e-30f, 1.1309962886447716e-31f,
    3.7699876288159054e-33f };

// ---------------------------------------------------------------------------
// f32 -> bf16 hi + bf16 lo (truncation split). Product error ~2^-16 relative.
// ---------------------------------------------------------------------------
__device__ __forceinline__ void split1(float v, short& h, short& l) {
    unsigned int b = __float_as_uint(v);
    h = (short)(b >> 16);
    float lo = v - __uint_as_float(b & 0xFFFF0000u);
    l = (short)(__float_as_uint(lo) >> 16);
}

__device__ __forceinline__ void split8(const float4 f0, const float4 f1,
                                       short8& h, short8& l) {
    float v[8] = {f0.x, f0.y, f0.z, f0.w, f1.x, f1.y, f1.z, f1.w};
#pragma unroll
    for (int i = 0; i < 8; ++i) { short hh, ll; split1(v[i], hh, ll); h[i] = hh; l[i] = ll; }
}

// ---------------------------------------------------------------------------
// Prep: split x and the 4 weight matrices into bf16 hi/lo planes, once.
// (validated rounds 4/5)
// ---------------------------------------------------------------------------
__global__ __launch_bounds__(256) void prep_kernel(
    const float* __restrict__ x,
    const float* __restrict__ Wq, const float* __restrict__ Wk,
    const float* __restrict__ Wv, const float* __restrict__ Wo,
    short* __restrict__ xh, short* __restrict__ xl,
    short* __restrict__ wh, short* __restrict__ wl) {
    const int t  = blockIdx.x * 256 + threadIdx.x;
    const int NX = BATCH * D / 8;   // 131072
    const int NW = D * D / 8;       // 8192 per weight
    const float* src; short* dh; short* dl; int idx;
    if (t < NX) { src = x; dh = xh; dl = xl; idx = t; }
    else {
        int u = t - NX; int w = u >> 13; idx = u & (NW - 1);
        if (w == 0)      src = Wq;
        else if (w == 1) src = Wk;
        else if (w == 2) src = Wv;
        else             src = Wo;
        dh = wh + w * (D * D); dl = wl + w * (D * D);
    }
    float4 f0 = ((const float4*)src)[idx * 2];
    float4 f1 = ((const float4*)src)[idx * 2 + 1];
    short8 h, l; split8(f0, f1, h, l);
    ((short8*)dh)[idx] = h;
    ((short8*)dl)[idx] = l;
}

// ---------------------------------------------------------------------------
// LDS-free split GEMM: C[b,i] = sum_k A[b,k]*W[i,k] + bias[i], with A and W
// given as pre-split bf16 hi/lo planes (row-major [*][256]).
// MFMA fragments are loaded DIRECTLY from global: lane (fr,fq) reads 16B at
// row (base+fr), k-offset k0+fq*8 -> 16x64B segments per instruction, fully
// L1/L2-cacheable, NO LDS (round-9 counters: 9.9M LDS bank-conflict cycles in
// the staged version), NO barriers, no split arithmetic in the hot loop.
// Block = 64x64 tile, 4 waves 2x2, wave tile 32x32 = 2x2 fragments of
// 16x16x32 bf16, 3 MFMAs per fragment (hi*lo + lo*hi + hi*hi).
// K-loop fully unrolled -> compiler pipelines the 8 loads/step under MFMA.
// ---------------------------------------------------------------------------
__device__ __forceinline__ void gemm_frag(
    const short* __restrict__ AhG, const short* __restrict__ AlG,
    const short* __restrict__ BhG, const short* __restrict__ BlG,
    const float* __restrict__ bias, float* __restrict__ C,
    int b0, int n0) {
    const int tid  = threadIdx.x;
    const int lane = tid & 63;
    const int wave = tid >> 6;
    const int wm   = wave >> 1;
    const int wn   = wave & 1;
    const int fr   = lane & 15;
    const int fq   = lane >> 4;

    const int arow = b0 + wm * 32 + fr;      // +16 for mi=1
    const int brow = n0 + wn * 32 + fr;      // +16 for ni=1

    const short* aH0 = AhG + (size_t)arow * D + fq * 8;
    const short* aL0 = AlG + (size_t)arow * D + fq * 8;
    const short* aH1 = aH0 + 16 * D;
    const short* aL1 = aL0 + 16 * D;
    const short* bH0 = BhG + (size_t)brow * D + fq * 8;
    const short* bL0 = BlG + (size_t)brow * D + fq * 8;
    const short* bH1 = bH0 + 16 * D;
    const short* bL1 = bL0 + 16 * D;

    f32x4 acc[2][2] = {};

#pragma unroll
    for (int k0 = 0; k0 < D; k0 += 32) {
        short8 arh[2], arl[2], brh[2], brl[2];
        arh[0] = *(const short8*)(aH0 + k0);
        arl[0] = *(const short8*)(aL0 + k0);
        arh[1] = *(const short8*)(aH1 + k0);
        arl[1] = *(const short8*)(aL1 + k0);
        brh[0] = *(const short8*)(bH0 + k0);
        brl[0] = *(const short8*)(bL0 + k0);
        brh[1] = *(const short8*)(bH1 + k0);
        brl[1] = *(const short8*)(bL1 + k0);

#pragma unroll
        for (int mi = 0; mi < 2; ++mi)
#pragma unroll
            for (int ni = 0; ni < 2; ++ni) {
                acc[mi][ni] = __builtin_amdgcn_mfma_f32_16x16x32_bf16(
                    arh[mi], brl[ni], acc[mi][ni], 0, 0, 0);
                acc[mi][ni] = __builtin_amdgcn_mfma_f32_16x16x32_bf16(
                    arl[mi], brh[ni], acc[mi][ni], 0, 0, 0);
                acc[mi][ni] = __builtin_amdgcn_mfma_f32_16x16x32_bf16(
                    arh[mi], brh[ni], acc[mi][ni], 0, 0, 0);
            }
    }

    // C/D layout 16x16x32: col = lane&15, row = (lane>>4)*4 + reg
    const int fq4 = fq * 4;
#pragma unroll
    for (int ni = 0; ni < 2; ++ni) {
        const int col = n0 + wn * 32 + ni * 16 + fr;
        const float bvv = bias[col];
#pragma unroll
        for (int mi = 0; mi < 2; ++mi) {
            const int rbase = b0 + wm * 32 + mi * 16 + fq4;
#pragma unroll
            for (int r = 0; r < 4; ++r)
                C[(size_t)(rbase + r) * D + col] = acc[mi][ni][r] + bvv;
        }
    }
}

// qkv: grid (64, 4, 3) = 768 blocks. Note: the 12 blocks sharing an x-tile
// have block-ids differing by multiples of 8 -> same XCD -> L2-local reuse.
__global__ __launch_bounds__(256) void qkv_kernel(
    const short* __restrict__ xh, const short* __restrict__ xl,
    const short* __restrict__ wh, const short* __restrict__ wl,
    const float* __restrict__ bq, const float* __restrict__ bk,
    const float* __restrict__ bv,
    float* __restrict__ Qo, float* __restrict__ Ko, float* __restrict__ Vo) {
    const int z = blockIdx.z;
    const float* bias = (z == 0) ? bq : (z == 1) ? bk : bv;
    float*       C    = (z == 0) ? Qo : (z == 1) ? Ko : Vo;
    gemm_frag(xh, xl, wh + (size_t)z * D * D, wl + (size_t)z * D * D,
              bias, C, blockIdx.x * 64, blockIdx.y * 64);
}

// oproj: grid (64, 4) = 256 blocks; A = attn output planes.
__global__ __launch_bounds__(256) void oproj_kernel(
    const short* __restrict__ Abh, const short* __restrict__ Abl,
    const short* __restrict__ wh, const short* __restrict__ wl,
    const float* __restrict__ bo, float* __restrict__ C) {
    gemm_frag(Abh, Abl, wh + 3 * (size_t)D * D, wl + 3 * (size_t)D * D,
              bo, C, blockIdx.x * 64, blockIdx.y * 64);
}

// ---------------------------------------------------------------------------
// Per-wave moment attention (validated rounds 3/4/5/8/9):
// rank-1 energy => exp Taylor collapses the j-sum into 31 moments
//   S_n = sum_j k_j^n, M_n = sum_j k_j^n v_j;  out_i = num(q_i)/den(q_i).
// k centered per-sample (softmax shift-invariant over j) => |q*k| <~ 5.5,
// tail < 1e-10. 2-pass LDS-transpose reduction on a wave-private slice
// (no barriers; same-wave LDS RAW ordered by lgkmcnt). Emits Ab pre-split
// (bf16 hi/lo) and attention_weights = 1/256 (softmax rows sum to 1).
// ---------------------------------------------------------------------------
__device__ __forceinline__ void attn_wave(
    int s, int l,
    const float* __restrict__ Q, const float* __restrict__ K,
    const float* __restrict__ V,
    float (*part)[66][2], float (*coef)[2],
    short* __restrict__ Abh, short* __restrict__ Abl,
    float* __restrict__ attn_w) {
    float4 k4 = *(const float4*)&K[(size_t)s * D + 4 * l];
    float4 v4 = *(const float4*)&V[(size_t)s * D + 4 * l];

    float ksum = (k4.x + k4.y) + (k4.z + k4.w);
#pragma unroll
    for (int off = 32; off; off >>= 1) ksum += __shfl_xor(ksum, off);
    const float kbar = ksum * (1.0f / 256.0f);
    float ks[4] = {k4.x - kbar, k4.y - kbar, k4.z - kbar, k4.w - kbar};
    float vs[4] = {v4.x, v4.y, v4.z, v4.w};

    const int rn = l & 15;
    const int sb = (l & 16) ? 32 : 0;

    float p[4] = {1.f, 1.f, 1.f, 1.f};
#pragma unroll
    for (int pass = 0; pass < 2; ++pass) {
        const int nlo  = pass ? 16 : 0;
        const int ncnt = pass ? (NMOM - 16) : 16;   // 15 or 16

        for (int nn = 0; nn < ncnt; ++nn) {
            if (nlo + nn > 0) {
#pragma unroll
                for (int u = 0; u < 4; ++u) p[u] *= ks[u];
            }
            float sv = (p[0] + p[1]) + (p[2] + p[3]);
            float mv = fmaf(p[0], vs[0],
                       fmaf(p[1], vs[1],
                       fmaf(p[2], vs[2], p[3] * vs[3])));
            float2 w2; w2.x = sv; w2.y = mv;
            *(float2*)&part[nn][l][0] = w2;        // wave-private slice
        }

        float2 acc2; acc2.x = 0.f; acc2.y = 0.f;
        if (l < 32) {
#pragma unroll
            for (int t = 0; t < 32; ++t) {
                float2 r2 = *(const float2*)&part[rn][sb + t][0];
                acc2.x += r2.x; acc2.y += r2.y;
            }
        }
        acc2.x += __shfl_xor(acc2.x, 16);
        acc2.y += __shfl_xor(acc2.y, 16);
        if (l < ncnt) {
            const int n = nlo + l;
            float2 c2; c2.x = acc2.x * INVFACT[n]; c2.y = acc2.y * INVFACT[n];
            *(float2*)&coef[n][0] = c2;
        }
    }

    float4 q4 = *(const float4*)&Q[(size_t)s * D + 4 * l];
    float qs[4] = {q4.x, q4.y, q4.z, q4.w};
    float de[4], nu[4];
    {
        float2 c2 = *(const float2*)&coef[NMOM - 1][0];
#pragma unroll
        for (int u = 0; u < 4; ++u) { de[u] = c2.x; nu[u] = c2.y; }
    }
#pragma unroll
    for (int n = NMOM - 2; n >= 0; --n) {
        float2 c2 = *(const float2*)&coef[n][0];
#pragma unroll
        for (int u = 0; u < 4; ++u) {
            de[u] = fmaf(de[u], qs[u], c2.x);
            nu[u] = fmaf(nu[u], qs[u], c2.y);
        }
    }

    short4e oh, ol;
#pragma unroll
    for (int u = 0; u < 4; ++u) {
        float o = nu[u] * __builtin_amdgcn_rcpf(de[u]);
        short hh, ll; split1(o, hh, ll);
        oh[u] = hh; ol[u] = ll;
    }
    *(short4e*)&Abh[(size_t)s * D + 4 * l] = oh;
    *(short4e*)&Abl[(size_t)s * D + 4 * l] = ol;

    float4 w4 = {1.0f/256.0f, 1.0f/256.0f, 1.0f/256.0f, 1.0f/256.0f};
    *(float4*)&attn_w[(size_t)s * D + 4 * l] = w4;
}

__global__ __launch_bounds__(256) void attn_kernel(
    const float* __restrict__ Q, const float* __restrict__ K,
    const float* __restrict__ V,
    short* __restrict__ Abh, short* __restrict__ Abl,
    float* __restrict__ attn_w) {
    __shared__ float part[4][16][66][2];
    __shared__ float coef[4][NMOM][2];
    const int w = threadIdx.x >> 6;
    const int l = threadIdx.x & 63;
    attn_wave(blockIdx.x * 4 + w, l, Q, K, V, part[w], coef[w],
              Abh, Abl, attn_w);
}

// ---------------------------------------------------------------------------
extern "C" void kernel_launch(void* const* d_in, const int* in_sizes, int n_in,
                              void* d_out, int out_size, void* d_ws, size_t ws_size,
                              hipStream_t stream) {
    const float* x  = (const float*)d_in[0];
    const float* Wq = (const float*)d_in[1];
    const float* bq = (const float*)d_in[2];
    const float* Wk = (const float*)d_in[3];
    const float* bk = (const float*)d_in[4];
    const float* Wv = (const float*)d_in[5];
    const float* bv = (const float*)d_in[6];
    const float* Wo = (const float*)d_in[7];
    const float* bo = (const float*)d_in[8];

    float* out    = (float*)d_out;
    float* attn_w = out;                       // output 0: [4096,256] = 1/256
    float* out2   = out + (size_t)BATCH * D;   // output 1: [4096,256]

    char* wsp = (char*)d_ws;
    short* xh  = (short*)(wsp + 0);                          // 2 MB
    short* xl  = (short*)(wsp + (2u << 20));                 // 2 MB
    short* wh  = (short*)(wsp + (4u << 20));                 // 512 KB
    short* wl  = (short*)(wsp + (4u << 20) + (512u << 10));  // 512 KB
    float* Qb  = (float*)(wsp + (8u << 20));                 // 4 MB
    float* Kb  = (float*)(wsp + (12u << 20));                // 4 MB
    float* Vb  = (float*)(wsp + (16u << 20));                // 4 MB
    short* Abh = (short*)(wsp + (20u << 20));                // 2 MB
    short* Abl = (short*)(wsp + (22u << 20));                // 2 MB

    // 131072 + 32768 threads = 640 blocks of 256
    prep_kernel<<<640, 256, 0, stream>>>(x, Wq, Wk, Wv, Wo, xh, xl, wh, wl);

    dim3 gqkv(BATCH / 64, D / 64, 3);
    qkv_kernel<<<gqkv, 256, 0, stream>>>(xh, xl, wh, wl, bq, bk, bv, Qb, Kb, Vb);

    attn_kernel<<<BATCH / 4, 256, 0, stream>>>(Qb, Kb, Vb, Abh, Abl, attn_w);

    dim3 gout(BATCH / 64, D / 64, 1);
    oproj_kernel<<<gout, 256, 0, stream>>>(Abh, Abl, wh, wl, bo, out2);
}

// Round 11
// 33.158 us; speedup vs baseline: 1.6667x; 1.6667x over previous
//
#include <hip/hip_runtime.h>

#define D     256
#define BATCH 4096
#define NMOM  25   // Taylor terms n = 0..24; tail at |x|<=5.5 is < 3e-7 abs

typedef __attribute__((ext_vector_type(8))) short short8;
typedef __attribute__((ext_vector_type(4))) short short4e;
typedef __attribute__((ext_vector_type(4))) float f32x4;

__constant__ float INVFACT[NMOM] = {
    1.0f, 1.0f, 0.5f,
    1.6666666666666666e-01f, 4.1666666666666664e-02f, 8.3333333333333332e-03f,
    1.3888888888888889e-03f, 1.9841269841269841e-04f, 2.4801587301587302e-05f,
    2.7557319223985893e-06f, 2.7557319223985888e-07f, 2.5052108385441720e-08f,
    2.0876756987868100e-09f, 1.6059043836821613e-10f, 1.1470745597729725e-11f,
    7.6471637318198164e-13f, 4.7794773323873853e-14f, 2.8114572543455206e-15f,
    1.5619206968586225e-16f, 8.2206352466243295e-18f, 4.1103176233121648e-19f,
    1.9572941063391263e-20f, 8.8967913924505741e-22f, 3.8681701706306843e-23f,
    1.6117375710961184e-24f };

// ---------------------------------------------------------------------------
// f32 -> bf16 hi + bf16 lo (truncation split). Product error ~2^-16 relative.
// ---------------------------------------------------------------------------
__device__ __forceinline__ void split1(float v, short& h, short& l) {
    unsigned int b = __float_as_uint(v);
    h = (short)(b >> 16);
    float lo = v - __uint_as_float(b & 0xFFFF0000u);
    l = (short)(__float_as_uint(lo) >> 16);
}

__device__ __forceinline__ void split8(const float4 f0, const float4 f1,
                                       short8& h, short8& l) {
    float v[8] = {f0.x, f0.y, f0.z, f0.w, f1.x, f1.y, f1.z, f1.w};
#pragma unroll
    for (int i = 0; i < 8; ++i) { short hh, ll; split1(v[i], hh, ll); h[i] = hh; l[i] = ll; }
}

// ---------------------------------------------------------------------------
// QKV GEMM — EXACT round-3/8 form (validated 3x, 33.4us config):
// C[b,i] = sum_k x[b,k]*Wz[i,k] + bias[i]; in-kernel split staging,
// 64x64 tile, 4 waves 2x2, wave tile 32x32, 16x16x32 bf16, 3-MFMA split,
// padded [.][40] LDS rows (b128 quad-uniform, conflict-free),
// loads -> barrier -> ds_write -> barrier -> MFMA (no prefetch).
// Grid (64,4,3) = 768 blocks -> 3 blocks/CU.
// ---------------------------------------------------------------------------
__global__ __launch_bounds__(256) void qkv_kernel(
    const float* __restrict__ x,
    const float* __restrict__ Wq, const float* __restrict__ bq,
    const float* __restrict__ Wk, const float* __restrict__ bk,
    const float* __restrict__ Wv, const float* __restrict__ bv,
    float* __restrict__ Qo, float* __restrict__ Ko, float* __restrict__ Vo) {
    __shared__ short Ah[64][40], Al[64][40];
    __shared__ short Bh[64][40], Bl[64][40];

    const int z = blockIdx.z;
    const float* W    = (z == 0) ? Wq : (z == 1) ? Wk : Wv;
    const float* bias = (z == 0) ? bq : (z == 1) ? bk : bv;
    float*       C    = (z == 0) ? Qo : (z == 1) ? Ko : Vo;

    const int b0 = blockIdx.x * 64, n0 = blockIdx.y * 64;
    const int tid  = threadIdx.x;
    const int lane = tid & 63;
    const int wave = tid >> 6;
    const int wm   = wave >> 1;
    const int wn   = wave & 1;
    const int fr   = lane & 15;
    const int fq   = lane >> 4;
    const int sr   = tid >> 2;          // staging row 0..63
    const int sq   = tid & 3;           // staging k-quarter (8 f32)

    f32x4 acc[2][2] = {};

    const float* aBase = x + (size_t)(b0 + sr) * D + sq * 8;
    const float* wBase = W + (size_t)(n0 + sr) * D + sq * 8;

    for (int k0 = 0; k0 < D; k0 += 32) {
        float4 a0 = *(const float4*)(aBase + k0);
        float4 a1 = *(const float4*)(aBase + k0 + 4);
        float4 w0 = *(const float4*)(wBase + k0);
        float4 w1 = *(const float4*)(wBase + k0 + 4);

        __syncthreads();   // previous tile fully consumed

        short8 h, l;
        split8(a0, a1, h, l);
        *(short8*)&Ah[sr][sq * 8] = h;
        *(short8*)&Al[sr][sq * 8] = l;
        split8(w0, w1, h, l);
        *(short8*)&Bh[sr][sq * 8] = h;
        *(short8*)&Bl[sr][sq * 8] = l;

        __syncthreads();

        short8 arh[2], arl[2], brh[2], brl[2];
#pragma unroll
        for (int mi = 0; mi < 2; ++mi) {
            const int r = wm * 32 + mi * 16 + fr;
            arh[mi] = *(const short8*)&Ah[r][fq * 8];
            arl[mi] = *(const short8*)&Al[r][fq * 8];
        }
#pragma unroll
        for (int ni = 0; ni < 2; ++ni) {
            const int r = wn * 32 + ni * 16 + fr;
            brh[ni] = *(const short8*)&Bh[r][fq * 8];
            brl[ni] = *(const short8*)&Bl[r][fq * 8];
        }
#pragma unroll
        for (int mi = 0; mi < 2; ++mi)
#pragma unroll
            for (int ni = 0; ni < 2; ++ni) {
                acc[mi][ni] = __builtin_amdgcn_mfma_f32_16x16x32_bf16(
                    arh[mi], brl[ni], acc[mi][ni], 0, 0, 0);
                acc[mi][ni] = __builtin_amdgcn_mfma_f32_16x16x32_bf16(
                    arl[mi], brh[ni], acc[mi][ni], 0, 0, 0);
                acc[mi][ni] = __builtin_amdgcn_mfma_f32_16x16x32_bf16(
                    arh[mi], brh[ni], acc[mi][ni], 0, 0, 0);
            }
    }

    // C/D layout 16x16x32: col = lane&15, row = (lane>>4)*4 + reg
#pragma unroll
    for (int ni = 0; ni < 2; ++ni) {
        const int col = n0 + wn * 32 + ni * 16 + fr;
        const float bvv = bias[col];
#pragma unroll
        for (int mi = 0; mi < 2; ++mi) {
            const int rbase = b0 + wm * 32 + mi * 16 + fq * 4;
#pragma unroll
            for (int r = 0; r < 4; ++r)
                C[(size_t)(rbase + r) * D + col] = acc[mi][ni][r] + bvv;
        }
    }
}

// ---------------------------------------------------------------------------
// Moment-based attention — EXACT round-3 structure (validated, ~13.6us):
// one 64-thread block per sample; 2-pass [16][65][2] LDS transpose reduce
// (stride 130 words = 2 mod 32 -> banks 2*rn+h all distinct, free 2-way;
// do NOT replace with the float2 variant: stride 132 = 4-way, R8 regression).
// Changes vs R3: NMOM 31->25 (tail < 3e-7 abs at |q*k|<=5.5) and output
// written pre-split (bf16 hi/lo, R8-validated) so oproj stages A by copy.
// attention_weights = 1/256 exactly (softmax rows sum to 1).
// ---------------------------------------------------------------------------
__global__ __launch_bounds__(64) void attn_kernel(
    const float* __restrict__ Q, const float* __restrict__ K,
    const float* __restrict__ V,
    short* __restrict__ Abh, short* __restrict__ Abl,
    float* __restrict__ attn_w) {
    __shared__ float part[16][65][2];   // [n][lane(padded)][{s,m}]
    __shared__ float coef[NMOM][2];     // [n][{S_n/n!, M_n/n!}]

    const int b = blockIdx.x;
    const int l = threadIdx.x;          // 0..63
    const int c    = l & 31;
    const int half = l >> 5;

    float4 k4 = *(const float4*)&K[(size_t)b * D + 4 * l];
    float4 v4 = *(const float4*)&V[(size_t)b * D + 4 * l];

    // center k (softmax over j is shift-invariant)
    float ksum = (k4.x + k4.y) + (k4.z + k4.w);
#pragma unroll
    for (int off = 32; off; off >>= 1) ksum += __shfl_xor(ksum, off);
    const float kbar = ksum * (1.0f / 256.0f);
    float ks[4] = {k4.x - kbar, k4.y - kbar, k4.z - kbar, k4.w - kbar};
    float vs[4] = {v4.x, v4.y, v4.z, v4.w};

    float p[4] = {1.f, 1.f, 1.f, 1.f};  // k^n, starts at n=0

#pragma unroll
    for (int pass = 0; pass < 2; ++pass) {
        const int nlo  = pass ? 16 : 0;
        const int ncnt = pass ? (NMOM - 16) : 16;   // 16 or 9

        for (int nn = 0; nn < ncnt; ++nn) {
            if (nlo + nn > 0) {
#pragma unroll
                for (int u = 0; u < 4; ++u) p[u] *= ks[u];
            }
            float s = (p[0] + p[1]) + (p[2] + p[3]);
            float m = fmaf(p[0], vs[0],
                      fmaf(p[1], vs[1],
                      fmaf(p[2], vs[2], p[3] * vs[3])));
            part[nn][l][0] = s;
            part[nn][l][1] = m;
        }
        __syncthreads();

        const int nvals = ncnt * 2;                 // 32 or 18
        float acc = 0.f;
        if (c < nvals) {
            const int rn = c >> 1, h = c & 1;
            const float* pp = &part[rn][half * 32][h];
#pragma unroll
            for (int t = 0; t < 32; ++t) acc += pp[2 * t];
        }
        acc += __shfl_xor(acc, 32);                 // combine lane halves
        if (half == 0 && c < nvals) {
            const int n = nlo + (c >> 1);
            coef[n][c & 1] = acc * INVFACT[n];
        }
        __syncthreads();
    }

    // Horner evaluation at the 4 q values this lane owns
    float4 q4 = *(const float4*)&Q[(size_t)b * D + 4 * l];
    float qs[4] = {q4.x, q4.y, q4.z, q4.w};
    float de[4], nu[4];
#pragma unroll
    for (int u = 0; u < 4; ++u) {
        de[u] = coef[NMOM - 1][0];
        nu[u] = coef[NMOM - 1][1];
    }
#pragma unroll
    for (int n = NMOM - 2; n >= 0; --n) {
        const float cs = coef[n][0];
        const float cm = coef[n][1];
#pragma unroll
        for (int u = 0; u < 4; ++u) {
            de[u] = fmaf(de[u], qs[u], cs);
            nu[u] = fmaf(nu[u], qs[u], cm);
        }
    }

    short4e oh, ol;
#pragma unroll
    for (int u = 0; u < 4; ++u) {
        float o = nu[u] * __builtin_amdgcn_rcpf(de[u]);
        short hh, ll; split1(o, hh, ll);
        oh[u] = hh; ol[u] = ll;
    }
    *(short4e*)&Abh[(size_t)b * D + 4 * l] = oh;
    *(short4e*)&Abl[(size_t)b * D + 4 * l] = ol;

    float4 w4 = {1.0f/256.0f, 1.0f/256.0f, 1.0f/256.0f, 1.0f/256.0f};
    *(float4*)&attn_w[(size_t)b * D + 4 * l] = w4;
}

// ---------------------------------------------------------------------------
// oproj — EXACT round-8 form (validated): A pre-split by attn (copy staging),
// Wo split in-kernel, same barrier structure, grid (64,4) = 256 blocks.
// ---------------------------------------------------------------------------
__global__ __launch_bounds__(256) void oproj_kernel(
    const short* __restrict__ AhG, const short* __restrict__ AlG,
    const float* __restrict__ Wo, const float* __restrict__ bo,
    float* __restrict__ C) {
    __shared__ short Ah[64][40], Al[64][40];
    __shared__ short Bh[64][40], Bl[64][40];

    const int b0 = blockIdx.x * 64, n0 = blockIdx.y * 64;
    const int tid  = threadIdx.x;
    const int lane = tid & 63;
    const int wave = tid >> 6;
    const int wm   = wave >> 1;
    const int wn   = wave & 1;
    const int fr   = lane & 15;
    const int fq   = lane >> 4;
    const int sr   = tid >> 2;
    const int sq   = tid & 3;

    f32x4 acc[2][2] = {};

    const short* aH    = AhG + (size_t)(b0 + sr) * D + sq * 8;
    const short* aL    = AlG + (size_t)(b0 + sr) * D + sq * 8;
    const float* wBase = Wo + (size_t)(n0 + sr) * D + sq * 8;

    for (int k0 = 0; k0 < D; k0 += 32) {
        short8 ah8 = *(const short8*)(aH + k0);
        short8 al8 = *(const short8*)(aL + k0);
        float4 w0  = *(const float4*)(wBase + k0);
        float4 w1  = *(const float4*)(wBase + k0 + 4);

        __syncthreads();   // previous tile fully consumed

        *(short8*)&Ah[sr][sq * 8] = ah8;
        *(short8*)&Al[sr][sq * 8] = al8;
        short8 h, l;
        split8(w0, w1, h, l);
        *(short8*)&Bh[sr][sq * 8] = h;
        *(short8*)&Bl[sr][sq * 8] = l;

        __syncthreads();

        short8 arh[2], arl[2], brh[2], brl[2];
#pragma unroll
        for (int mi = 0; mi < 2; ++mi) {
            const int r = wm * 32 + mi * 16 + fr;
            arh[mi] = *(const short8*)&Ah[r][fq * 8];
            arl[mi] = *(const short8*)&Al[r][fq * 8];
        }
#pragma unroll
        for (int ni = 0; ni < 2; ++ni) {
            const int r = wn * 32 + ni * 16 + fr;
            brh[ni] = *(const short8*)&Bh[r][fq * 8];
            brl[ni] = *(const short8*)&Bl[r][fq * 8];
        }
#pragma unroll
        for (int mi = 0; mi < 2; ++mi)
#pragma unroll
            for (int ni = 0; ni < 2; ++ni) {
                acc[mi][ni] = __builtin_amdgcn_mfma_f32_16x16x32_bf16(
                    arh[mi], brl[ni], acc[mi][ni], 0, 0, 0);
                acc[mi][ni] = __builtin_amdgcn_mfma_f32_16x16x32_bf16(
                    arl[mi], brh[ni], acc[mi][ni], 0, 0, 0);
                acc[mi][ni] = __builtin_amdgcn_mfma_f32_16x16x32_bf16(
                    arh[mi], brh[ni], acc[mi][ni], 0, 0, 0);
            }
    }

#pragma unroll
    for (int ni = 0; ni < 2; ++ni) {
        const int col = n0 + wn * 32 + ni * 16 + fr;
        const float bvv = bo[col];
#pragma unroll
        for (int mi = 0; mi < 2; ++mi) {
            const int rbase = b0 + wm * 32 + mi * 16 + fq * 4;
#pragma unroll
            for (int r = 0; r < 4; ++r)
                C[(size_t)(rbase + r) * D + col] = acc[mi][ni][r] + bvv;
        }
    }
}

// ---------------------------------------------------------------------------
extern "C" void kernel_launch(void* const* d_in, const int* in_sizes, int n_in,
                              void* d_out, int out_size, void* d_ws, size_t ws_size,
                              hipStream_t stream) {
    const float* x  = (const float*)d_in[0];
    const float* Wq = (const float*)d_in[1];
    const float* bq = (const float*)d_in[2];
    const float* Wk = (const float*)d_in[3];
    const float* bk = (const float*)d_in[4];
    const float* Wv = (const float*)d_in[5];
    const float* bv = (const float*)d_in[6];
    const float* Wo = (const float*)d_in[7];
    const float* bo = (const float*)d_in[8];

    float* out    = (float*)d_out;
    float* attn_w = out;                       // output 0: [4096,256] = 1/256
    float* out2   = out + (size_t)BATCH * D;   // output 1: [4096,256]

    char* wsp = (char*)d_ws;
    float* Qb  = (float*)(wsp + 0);              // 4 MB
    float* Kb  = (float*)(wsp + (4u << 20));     // 4 MB
    float* Vb  = (float*)(wsp + (8u << 20));     // 4 MB
    short* Abh = (short*)(wsp + (12u << 20));    // 2 MB
    short* Abl = (short*)(wsp + (14u << 20));    // 2 MB

    dim3 gqkv(BATCH / 64, D / 64, 3);
    qkv_kernel<<<gqkv, 256, 0, stream>>>(x, Wq, bq, Wk, bk, Wv, bv, Qb, Kb, Vb);

    attn_kernel<<<BATCH, 64, 0, stream>>>(Qb, Kb, Vb, Abh, Abl, attn_w);

    dim3 gout(BATCH / 64, D / 64, 1);
    oproj_kernel<<<gout, 256, 0, stream>>>(Abh, Abl, Wo, bo, out2);
}